// Round 12
// baseline (24.085 us; speedup 1.0000x reference)
//
#include <hip/hip_runtime.h>

#define NEG_SLOPE 0.01f

typedef _Float16 f16;
typedef _Float16 f16x4 __attribute__((ext_vector_type(4)));
typedef float    f32x4 __attribute__((ext_vector_type(4)));

__device__ __forceinline__ float leaky(float v) {
    return fmaxf(v, NEG_SLOPE * v);
}

// ---------------- Fully fused, 512-thr blocks, 1 row per wave ----------------
// 1024 blocks x 512 thr (8 waves). Block covers rows blockIdx*8 .. +7 (same b).
// Wave wv owns row bi = blockIdx*8+wv entirely -> no cross-wave reduce.
// Phase 1: 512 threads stage pj[512][16] f16 (swizzled, 1 j each);
//          per-wave node MLP (intra-wave LDS); per-wave sigmoid row -> LDS f32.
// Phase 2 (one barrier): 32 subtiles, prefetch-pipelined:
//          h1 = pk(pj4 + piu4, leaky); d1 = 2 chained MFMAs (hi/lo weights);
//          p[e] += sig*d1[e]; q[e] += sig*|d1[e]|   (leaky folded in epilogue)
// Epilogue: pp = 0.505*(p.w3) + 0.495*(q.w3) + bc3*vS + node; butterfly.
__global__ __launch_bounds__(512, 8) void fused_row(
    const float* __restrict__ x,
    const float* __restrict__ Wn1, const float* __restrict__ bn1,
    const float* __restrict__ Wn2, const float* __restrict__ bn2,
    const float* __restrict__ Wn3, const float* __restrict__ bn3,
    const float* __restrict__ Wc1, const float* __restrict__ bc1,
    const float* __restrict__ Wc2, const float* __restrict__ bc2,
    const float* __restrict__ Wc3, const float* __restrict__ bc3,
    const float* __restrict__ A_param,
    float* __restrict__ out)
{
    __shared__ unsigned char pjbuf[512 * 32];   // f16 [512][16], swizzled
    __shared__ float shn[8][64];                // node h1, per wave
    __shared__ float sigbuf[8][512];            // sigmoid row, per wave

    const int t  = threadIdx.x;
    const int l  = t & 63;
    const int wv = t >> 6;            // 0..7
    const int p  = l & 15;            // pair slot within 16-j tile
    const int g  = l >> 4;            // channel group
    const int c4 = g << 2;
    const int bi = blockIdx.x * 8 + wv;   // b*512 + i
    const int bb = bi >> 9;
    const int i  = bi & 511;

    const float* xb = x + bb * 1024;  // x[b][j][2]

    // ---- Phase 1a: stage pj (f16) into LDS; thread t covers j = t ----
    {
        const int j = t;
        const float2 xj = *reinterpret_cast<const float2*>(xb + j * 2);
        f16 v[16];
        #pragma unroll
        for (int c = 0; c < 16; ++c)
            v[c] = (f16)fmaf(xj.x, Wc1[c], xj.y * Wc1[16 + c]);
        const int sw = ((j >> 2) & 3) << 3;
        #pragma unroll
        for (int gg = 0; gg < 4; ++gg) {
            const int addr = j * 32 + ((gg << 3) ^ sw);
            *reinterpret_cast<f16x4*>(pjbuf + addr) =
                (f16x4){v[4*gg], v[4*gg+1], v[4*gg+2], v[4*gg+3]};
        }
    }

    const float2 xi = *reinterpret_cast<const float2*>(xb + i * 2);

    // ---- Phase 1b: weight fragments + piu ----
    f16x4 w2lo, w2hi, piu4;
    f32x4 c1;
    float w3r[4];
    #pragma unroll
    for (int e = 0; e < 4; ++e) {
        const int c = c4 + e;
        const float w2 = Wc2[c * 16 + p];
        const f16 hw = (f16)w2;
        w2hi[e] = hw; w2lo[e] = (f16)(w2 - (float)hw);
        c1[e]  = bc2[c];
        w3r[e] = Wc3[c];
        piu4[e] = (f16)fmaf(xi.x, Wc1[32 + c], fmaf(xi.y, Wc1[48 + c], bc1[c]));
    }
    const f16x4 slope4 = {(f16)NEG_SLOPE, (f16)NEG_SLOPE, (f16)NEG_SLOPE, (f16)NEG_SLOPE};

    // ---- Phase 1c: node MLP for this row (intra-wave LDS, split chains) ----
    const float h1n = leaky(fmaf(xi.x, Wn1[l], fmaf(xi.y, Wn1[64 + l], bn1[l])));
    shn[wv][l] = h1n;
    float n0 = bn2[l], n1 = 0.f;
    #pragma unroll 8
    for (int c = 0; c < 64; c += 2) {
        n0 = fmaf(shn[wv][c],     Wn2[c * 64 + l],       n0);
        n1 = fmaf(shn[wv][c + 1], Wn2[(c + 1) * 64 + l], n1);
    }
    const float pn = leaky(n0 + n1) * Wn3[l];

    // ---- Phase 1d: sigmoid row -> LDS (intra-wave use) ----
    float vS = 0.f;
    const float* Ar = A_param + i * 512;
    #pragma unroll
    for (int s = 0; s < 8; ++s) {
        const int j = s * 64 + l;
        float sg = __fdividef(1.f, 1.f + __expf(-Ar[j]));
        if (j == i) sg = 0.f;         // sigmoid(0 - 1e5) == 0 in f32
        vS += sg;
        sigbuf[wv][j] = sg;
    }

    __syncthreads();   // pjbuf staging complete (shn/sigbuf are intra-wave)

    // ---- Phase 2: 32 subtiles, prefetch-pipelined ----
    const int rbase = p * 32 + ((g << 3) ^ (((p >> 2) & 3) << 3));
    float p0=0.f,p1=0.f,p2=0.f,p3=0.f, q0=0.f,q1=0.f,q2=0.f,q3=0.f;

    f16x4 pjc = *reinterpret_cast<const f16x4*>(pjbuf + rbase);
    float sgc = sigbuf[wv][p];

    #pragma unroll 4
    for (int T = 0; T < 32; ++T) {
        const int Tn = (T + 1) & 31;   // wraparound dummy prefetch on last iter
        const f16x4 pjn = *reinterpret_cast<const f16x4*>(pjbuf + rbase + Tn * 512);
        const float sgn = sigbuf[wv][Tn * 16 + p];

        const f16x4 s4 = pjc + piu4;
        const f16x4 b1 = __builtin_elementwise_max(s4, s4 * slope4);

        f32x4 d1 = __builtin_amdgcn_mfma_f32_16x16x16f16(w2lo, b1, c1, 0, 0, 0);
        d1 = __builtin_amdgcn_mfma_f32_16x16x16f16(w2hi, b1, d1, 0, 0, 0);

        p0 = fmaf(sgc, d1[0], p0);  q0 = fmaf(sgc, fabsf(d1[0]), q0);
        p1 = fmaf(sgc, d1[1], p1);  q1 = fmaf(sgc, fabsf(d1[1]), q1);
        p2 = fmaf(sgc, d1[2], p2);  q2 = fmaf(sgc, fabsf(d1[2]), q2);
        p3 = fmaf(sgc, d1[3], p3);  q3 = fmaf(sgc, fabsf(d1[3]), q3);

        pjc = pjn; sgc = sgn;
    }

    // ---- Epilogue: leaky fold, node, bc3 term, butterfly ----
    const float dp = fmaf(p0, w3r[0], fmaf(p1, w3r[1], fmaf(p2, w3r[2], p3 * w3r[3])));
    const float dq = fmaf(q0, w3r[0], fmaf(q1, w3r[1], fmaf(q2, w3r[2], q3 * w3r[3])));
    float pp = fmaf(0.505f, dp, 0.495f * dq);
    pp = fmaf(bc3[0], vS, pp) + pn;

    #pragma unroll
    for (int off = 32; off > 0; off >>= 1)
        pp += __shfl_xor(pp, off, 64);

    if (l == 0) {
        out[bi * 2 + 0] = xi.y;                // out0 = x[...,1]
        out[bi * 2 + 1] = pp + bn3[0];
    }
}

extern "C" void kernel_launch(void* const* d_in, const int* in_sizes, int n_in,
                              void* d_out, int out_size, void* d_ws, size_t ws_size,
                              hipStream_t stream) {
    const float* x       = (const float*)d_in[0];
    const float* Wn1     = (const float*)d_in[1];
    const float* bn1     = (const float*)d_in[2];
    const float* Wn2     = (const float*)d_in[3];
    const float* bn2     = (const float*)d_in[4];
    const float* Wn3     = (const float*)d_in[5];
    const float* bn3     = (const float*)d_in[6];
    const float* Wc1     = (const float*)d_in[7];
    const float* bc1     = (const float*)d_in[8];
    const float* Wc2     = (const float*)d_in[9];
    const float* bc2     = (const float*)d_in[10];
    const float* Wc3     = (const float*)d_in[11];
    const float* bc3     = (const float*)d_in[12];
    const float* A_param = (const float*)d_in[13];
    float* out = (float*)d_out;

    const int BN = 16 * 512;          // 8192 rows; 8 per block (1 per wave)

    fused_row<<<BN / 8, 512, 0, stream>>>(x, Wn1, bn1, Wn2, bn2, Wn3, bn3,
                                          Wc1, bc1, Wc2, bc2, Wc3, bc3,
                                          A_param, out);
}